// Round 3
// baseline (84.690 us; speedup 1.0000x reference)
//
#include <hip/hip_runtime.h>
#include <hip/hip_bf16.h>
#include <math.h>

#define NB   2048
#define NC   1000
#define DDIM 128
#define LDT  136      // LDS row stride in bf16 (+8 pad; 272 B rows keep 16B align)
#define NPB  136      // compact triangular proto blocks (by<=bx<16)
#define NBLK 512      // fused grid: 16 col-tiles x 32 row-tiles
#define CNT_IDX 256   // int "proto done" counter lives at ws[256]

typedef __attribute__((ext_vector_type(8))) short  short8;
typedef __attribute__((ext_vector_type(4))) float  floatx4;

__device__ __forceinline__ float bf2f(unsigned short b) {
    union { float f; unsigned int u; } v; v.u = ((unsigned int)b) << 16;
    return v.f;
}

// stage 64 rows x 128 k of fp32 -> bf16 LDS tile (RNE), coalesced float4 reads
__device__ __forceinline__ void stage_cvt(const float* __restrict__ src, int row0, int clampr,
                                          unsigned short* __restrict__ lds, int t) {
    #pragma unroll
    for (int i = 0; i < 8; ++i) {
        int c = (i * 256 + t) * 4;
        int r = c >> 7, k = c & 127;
        int gr = row0 + r; if (gr > clampr) gr = clampr;
        float4 v = *(const float4*)(src + gr * DDIM + k);
        union { __hip_bfloat162 h; unsigned int u; } p0, p1;
        p0.h = __float22bfloat162_rn(make_float2(v.x, v.y));
        p1.h = __float22bfloat162_rn(make_float2(v.z, v.w));
        uint2 st; st.x = p0.u; st.y = p1.u;
        *(uint2*)(lds + r * LDT + k) = st;
    }
}

// per-row squared norms of the ROUNDED bf16 values; 4 lanes per row
__device__ __forceinline__ void norm64(const unsigned short* __restrict__ tile,
                                       float* __restrict__ nrm, int t) {
    int r = t >> 2, seg = t & 3;
    const unsigned short* p = tile + r * LDT + seg * 32;
    float q = 0.0f;
    #pragma unroll
    for (int j = 0; j < 4; ++j) {
        short8 v = *(const short8*)(p + j * 8);
        #pragma unroll
        for (int e = 0; e < 8; ++e) { float f = bf2f((unsigned short)v[e]); q = fmaf(f, f, q); }
    }
    q += __shfl_xor(q, 1);
    q += __shfl_xor(q, 2);
    if (seg == 0) nrm[r] = q;
}

// zero the proto-done counter each iteration (workspace is re-poisoned between runs)
__global__ void init_kernel(float* __restrict__ ws) {
    *(int*)(ws + CNT_IDX) = 0;
}

// ---- fused: proto partial (bid<136) then dist tile; spin only in the epilogue ----
__global__ __launch_bounds__(256, 2) void fused_kernel(const float* __restrict__ F,
                                                       const float* __restrict__ W,
                                                       float* __restrict__ ws,
                                                       float* __restrict__ out) {
    __shared__ __align__(16) unsigned short As[64 * LDT];
    __shared__ __align__(16) unsigned short Bs[64 * LDT];
    __shared__ float nA[64], nB[64], red[4], red2[4];
    const int bid = blockIdx.x;
    const int t = threadIdx.x;
    const int lane = t & 63, w = t >> 6;
    const int lm = lane & 15, q = lane >> 4;

    if (bid < NPB) {
        // ---------- proto tile: compact upper triangle, bit-identical math ----------
        int by = 0, base = 0;                  // map bid -> (by<=bx<16)
        while (base + (16 - by) <= bid) { base += 16 - by; ++by; }
        int bx = by + (bid - base);
        int prow0 = by * 64, pcol0 = bx * 64;
        stage_cvt(W, prow0, NC - 1, As, t);
        stage_cvt(W, pcol0, NC - 1, Bs, t);
        __syncthreads();
        norm64(As, nA, t);
        norm64(Bs, nB, t);
        int wm = (w >> 1) * 32, wn = (w & 1) * 32;
        floatx4 acc[2][2] = {{{0,0,0,0},{0,0,0,0}},{{0,0,0,0},{0,0,0,0}}};
        #pragma unroll
        for (int ks = 0; ks < 4; ++ks) {
            int ko = ks * 32 + q * 8;
            short8 a0 = *(const short8*)(As + (wm + lm) * LDT + ko);
            short8 a1 = *(const short8*)(As + (wm + 16 + lm) * LDT + ko);
            short8 b0 = *(const short8*)(Bs + (wn + lm) * LDT + ko);
            short8 b1 = *(const short8*)(Bs + (wn + 16 + lm) * LDT + ko);
            acc[0][0] = __builtin_amdgcn_mfma_f32_16x16x32_bf16(a0, b0, acc[0][0], 0, 0, 0);
            acc[0][1] = __builtin_amdgcn_mfma_f32_16x16x32_bf16(a0, b1, acc[0][1], 0, 0, 0);
            acc[1][0] = __builtin_amdgcn_mfma_f32_16x16x32_bf16(a1, b0, acc[1][0], 0, 0, 0);
            acc[1][1] = __builtin_amdgcn_mfma_f32_16x16x32_bf16(a1, b1, acc[1][1], 0, 0, 0);
        }
        __syncthreads();                       // norms visible
        float local = 0.0f;
        #pragma unroll
        for (int ti = 0; ti < 2; ++ti)
            #pragma unroll
            for (int tj = 0; tj < 2; ++tj) {
                int lc2 = wn + tj * 16 + lm;
                if (pcol0 + lc2 < NC) {
                    float n2 = nB[lc2];
                    #pragma unroll
                    for (int r = 0; r < 4; ++r) {
                        int lc1 = wm + ti * 16 + q * 4 + r;
                        if (prow0 + lc1 < NC) {
                            float d2 = nA[lc1] + n2 - 2.0f * acc[ti][tj][r];
                            local += sqrtf(fmaxf(d2, 0.0f));
                        }
                    }
                }
            }
        if (by != bx) local *= 2.0f;           // symmetric double-count
        #pragma unroll
        for (int off = 32; off > 0; off >>= 1) local += __shfl_down(local, off);
        if (lane == 0) red[w] = local;
        __syncthreads();
        if (t == 0) {
            float partial = red[0] + red[1] + red[2] + red[3];
            __hip_atomic_store(&ws[bid], partial, __ATOMIC_RELAXED, __HIP_MEMORY_SCOPE_AGENT);
            __hip_atomic_fetch_add((int*)(ws + CNT_IDX), 1,
                                   __ATOMIC_RELEASE, __HIP_MEMORY_SCOPE_AGENT);
        }
        __syncthreads();                       // LDS/norms free for reuse
    }

    // ---------- dist tile: swapped operands (m=c, n=b) for float4 stores ----------
    const int row0 = (bid >> 4) * 64;          // F rows
    const int col0 = (bid & 15) * 64;          // W rows
    stage_cvt(F, row0, NB - 1, As, t);         // As = F tile
    stage_cvt(W, col0, NC - 1, Bs, t);         // Bs = W tile
    __syncthreads();                           // staging visible
    norm64(As, nA, t);                         // nA = F norms
    norm64(Bs, nB, t);                         // nB = W norms
    int wc = (w >> 1) * 32, wb = (w & 1) * 32; // wave offsets: c (m-dim), b (n-dim)
    floatx4 acc[2][2] = {{{0,0,0,0},{0,0,0,0}},{{0,0,0,0},{0,0,0,0}}};
    #pragma unroll
    for (int ks = 0; ks < 4; ++ks) {
        int ko = ks * 32 + q * 8;
        short8 a0 = *(const short8*)(Bs + (wc + lm) * LDT + ko);       // A-frag = W
        short8 a1 = *(const short8*)(Bs + (wc + 16 + lm) * LDT + ko);
        short8 b0 = *(const short8*)(As + (wb + lm) * LDT + ko);       // B-frag = F
        short8 b1 = *(const short8*)(As + (wb + 16 + lm) * LDT + ko);
        acc[0][0] = __builtin_amdgcn_mfma_f32_16x16x32_bf16(a0, b0, acc[0][0], 0, 0, 0);
        acc[0][1] = __builtin_amdgcn_mfma_f32_16x16x32_bf16(a0, b1, acc[0][1], 0, 0, 0);
        acc[1][0] = __builtin_amdgcn_mfma_f32_16x16x32_bf16(a1, b0, acc[1][0], 0, 0, 0);
        acc[1][1] = __builtin_amdgcn_mfma_f32_16x16x32_bf16(a1, b1, acc[1][1], 0, 0, 0);
    }
    __syncthreads();                           // norms visible

    // spin: RELAXED polls (no per-iteration cache invalidate); one acquire at the end
    if (t == 0) {
        while (__hip_atomic_load((int*)(ws + CNT_IDX), __ATOMIC_RELAXED,
                                 __HIP_MEMORY_SCOPE_AGENT) < NPB)
            __builtin_amdgcn_s_sleep(8);
        // pair with producers' release RMW: one acquire load + agent acquire fence
        (void)__hip_atomic_load((int*)(ws + CNT_IDX), __ATOMIC_ACQUIRE,
                                __HIP_MEMORY_SCOPE_AGENT);
        __builtin_amdgcn_fence(__ATOMIC_ACQUIRE, "agent");
    }
    __syncthreads();
    float pv = (t < NPB)
        ? __hip_atomic_load(&ws[t], __ATOMIC_RELAXED, __HIP_MEMORY_SCOPE_AGENT)
        : 0.0f;
    #pragma unroll
    for (int off = 32; off > 0; off >>= 1) pv += __shfl_down(pv, off);
    if (lane == 0) red2[w] = pv;
    __syncthreads();
    float proto = red2[0] + red2[1] + red2[2] + red2[3];

    #pragma unroll
    for (int ci = 0; ci < 2; ++ci) {
        int lcb = wc + ci * 16 + q * 4;        // c_local base for this lane
        int cb  = col0 + lcb;                  // global c base (quad-aligned)
        if (cb < NC) {                         // NC%4==0: quad all-or-nothing
            float nw0 = nB[lcb], nw1 = nB[lcb + 1], nw2 = nB[lcb + 2], nw3 = nB[lcb + 3];
            #pragma unroll
            for (int bj = 0; bj < 2; ++bj) {
                int lb = wb + bj * 16 + lm;
                int bg = row0 + lb;            // global F row
                float nb_ = nA[lb];
                floatx4 d = acc[ci][bj];
                float4 o;
                o.x = proto - sqrtf(fmaxf(nw0 + nb_ - 2.0f * d[0], 0.0f));
                o.y = proto - sqrtf(fmaxf(nw1 + nb_ - 2.0f * d[1], 0.0f));
                o.z = proto - sqrtf(fmaxf(nw2 + nb_ - 2.0f * d[2], 0.0f));
                o.w = proto - sqrtf(fmaxf(nw3 + nb_ - 2.0f * d[3], 0.0f));
                *(float4*)(out + bg * NC + cb) = o;
            }
        }
    }
}

extern "C" void kernel_launch(void* const* d_in, const int* in_sizes, int n_in,
                              void* d_out, int out_size, void* d_ws, size_t ws_size,
                              hipStream_t stream) {
    const float* F  = (const float*)d_in[0];   // (2048,128)
    const float* Wm = (const float*)d_in[1];   // (1000,128)
    float* out = (float*)d_out;                // (2048,1000)
    float* ws  = (float*)d_ws;

    init_kernel<<<1, 1, 0, stream>>>(ws);
    fused_kernel<<<NBLK, 256, 0, stream>>>(F, Wm, ws, out);
}

// Round 4
// 82.470 us; speedup vs baseline: 1.0269x; 1.0269x over previous
//
#include <hip/hip_runtime.h>
#include <hip/hip_bf16.h>
#include <math.h>

#define NB   2048
#define NC   1000
#define DDIM 128
#define LDT  136      // LDS row stride in bf16 (+8 pad; 272 B rows keep 16B align)
#define NPROTO 136    // compact triangular proto blocks (by<=bx<16), bid 0..135
#define NDIST  512    // dist tiles: 32 row-tiles x 16 col-tiles, bid 136..647
#define NBLK (NPROTO + NDIST)
#define CNT_IDX 256   // int "proto done" counter lives at ws[256]

typedef __attribute__((ext_vector_type(8))) short  short8;
typedef __attribute__((ext_vector_type(4))) float  floatx4;

__device__ __forceinline__ float bf2f(unsigned short b) {
    union { float f; unsigned int u; } v; v.u = ((unsigned int)b) << 16;
    return v.f;
}

// stage 64 rows x 128 k of fp32 -> bf16 LDS tile (RNE), coalesced float4 reads
__device__ __forceinline__ void stage_cvt(const float* __restrict__ src, int row0, int clampr,
                                          unsigned short* __restrict__ lds, int t) {
    #pragma unroll
    for (int i = 0; i < 8; ++i) {
        int c = (i * 256 + t) * 4;
        int r = c >> 7, k = c & 127;
        int gr = row0 + r; if (gr > clampr) gr = clampr;
        float4 v = *(const float4*)(src + gr * DDIM + k);
        union { __hip_bfloat162 h; unsigned int u; } p0, p1;
        p0.h = __float22bfloat162_rn(make_float2(v.x, v.y));
        p1.h = __float22bfloat162_rn(make_float2(v.z, v.w));
        uint2 st; st.x = p0.u; st.y = p1.u;
        *(uint2*)(lds + r * LDT + k) = st;
    }
}

// per-row squared norms of the ROUNDED bf16 values; 4 lanes per row
__device__ __forceinline__ void norm64(const unsigned short* __restrict__ tile,
                                       float* __restrict__ nrm, int t) {
    int r = t >> 2, seg = t & 3;
    const unsigned short* p = tile + r * LDT + seg * 32;
    float q = 0.0f;
    #pragma unroll
    for (int j = 0; j < 4; ++j) {
        short8 v = *(const short8*)(p + j * 8);
        #pragma unroll
        for (int e = 0; e < 8; ++e) { float f = bf2f((unsigned short)v[e]); q = fmaf(f, f, q); }
    }
    q += __shfl_xor(q, 1);
    q += __shfl_xor(q, 2);
    if (seg == 0) nrm[r] = q;
}

// ---- one kernel: bid<136 = proto-only producers; bid>=136 = dist-only consumers ----
__global__ __launch_bounds__(256) void fused_kernel(const float* __restrict__ F,
                                                    const float* __restrict__ W,
                                                    float* __restrict__ ws,
                                                    float* __restrict__ out) {
    __shared__ __align__(16) unsigned short As[64 * LDT];
    __shared__ __align__(16) unsigned short Bs[64 * LDT];
    __shared__ float nA[64], nB[64], red[4], red2[4];
    const int bid = blockIdx.x;
    const int t = threadIdx.x;
    const int lane = t & 63, w = t >> 6;
    const int lm = lane & 15, q = lane >> 4;

    if (bid < NPROTO) {
        // ---------- proto tile: compact upper triangle, bit-identical math ----------
        int by = 0, base = 0;                  // map bid -> (by<=bx<16)
        while (base + (16 - by) <= bid) { base += 16 - by; ++by; }
        int bx = by + (bid - base);
        int prow0 = by * 64, pcol0 = bx * 64;
        stage_cvt(W, prow0, NC - 1, As, t);
        stage_cvt(W, pcol0, NC - 1, Bs, t);
        __syncthreads();
        norm64(As, nA, t);
        norm64(Bs, nB, t);
        int wm = (w >> 1) * 32, wn = (w & 1) * 32;
        floatx4 acc[2][2] = {{{0,0,0,0},{0,0,0,0}},{{0,0,0,0},{0,0,0,0}}};
        #pragma unroll
        for (int ks = 0; ks < 4; ++ks) {
            int ko = ks * 32 + q * 8;
            short8 a0 = *(const short8*)(As + (wm + lm) * LDT + ko);
            short8 a1 = *(const short8*)(As + (wm + 16 + lm) * LDT + ko);
            short8 b0 = *(const short8*)(Bs + (wn + lm) * LDT + ko);
            short8 b1 = *(const short8*)(Bs + (wn + 16 + lm) * LDT + ko);
            acc[0][0] = __builtin_amdgcn_mfma_f32_16x16x32_bf16(a0, b0, acc[0][0], 0, 0, 0);
            acc[0][1] = __builtin_amdgcn_mfma_f32_16x16x32_bf16(a0, b1, acc[0][1], 0, 0, 0);
            acc[1][0] = __builtin_amdgcn_mfma_f32_16x16x32_bf16(a1, b0, acc[1][0], 0, 0, 0);
            acc[1][1] = __builtin_amdgcn_mfma_f32_16x16x32_bf16(a1, b1, acc[1][1], 0, 0, 0);
        }
        __syncthreads();                       // norms visible
        float local = 0.0f;
        #pragma unroll
        for (int ti = 0; ti < 2; ++ti)
            #pragma unroll
            for (int tj = 0; tj < 2; ++tj) {
                int lc2 = wn + tj * 16 + lm;
                if (pcol0 + lc2 < NC) {
                    float n2 = nB[lc2];
                    #pragma unroll
                    for (int r = 0; r < 4; ++r) {
                        int lc1 = wm + ti * 16 + q * 4 + r;
                        if (prow0 + lc1 < NC) {
                            float d2 = nA[lc1] + n2 - 2.0f * acc[ti][tj][r];
                            local += sqrtf(fmaxf(d2, 0.0f));
                        }
                    }
                }
            }
        if (by != bx) local *= 2.0f;           // symmetric double-count
        #pragma unroll
        for (int off = 32; off > 0; off >>= 1) local += __shfl_down(local, off);
        if (lane == 0) red[w] = local;
        __syncthreads();
        if (t == 0) {
            float partial = red[0] + red[1] + red[2] + red[3];
            __hip_atomic_store(&ws[bid], partial, __ATOMIC_RELAXED, __HIP_MEMORY_SCOPE_AGENT);
            __hip_atomic_fetch_add((int*)(ws + CNT_IDX), 1,
                                   __ATOMIC_RELEASE, __HIP_MEMORY_SCOPE_AGENT);
        }
        return;                                // proto blocks are done
    }

    // ---------- dist tile: swapped operands (m=c, n=b) for float4 stores ----------
    const int did  = bid - NPROTO;             // 0..511
    const int row0 = (did >> 4) * 64;          // F rows
    const int col0 = (did & 15) * 64;          // W rows
    stage_cvt(F, row0, NB - 1, As, t);         // As = F tile
    stage_cvt(W, col0, NC - 1, Bs, t);         // Bs = W tile
    __syncthreads();                           // staging visible
    norm64(As, nA, t);                         // nA = F norms
    norm64(Bs, nB, t);                         // nB = W norms
    int wc = (w >> 1) * 32, wb = (w & 1) * 32; // wave offsets: c (m-dim), b (n-dim)
    floatx4 acc[2][2] = {{{0,0,0,0},{0,0,0,0}},{{0,0,0,0},{0,0,0,0}}};
    #pragma unroll
    for (int ks = 0; ks < 4; ++ks) {
        int ko = ks * 32 + q * 8;
        short8 a0 = *(const short8*)(Bs + (wc + lm) * LDT + ko);       // A-frag = W
        short8 a1 = *(const short8*)(Bs + (wc + 16 + lm) * LDT + ko);
        short8 b0 = *(const short8*)(As + (wb + lm) * LDT + ko);       // B-frag = F
        short8 b1 = *(const short8*)(As + (wb + 16 + lm) * LDT + ko);
        acc[0][0] = __builtin_amdgcn_mfma_f32_16x16x32_bf16(a0, b0, acc[0][0], 0, 0, 0);
        acc[0][1] = __builtin_amdgcn_mfma_f32_16x16x32_bf16(a0, b1, acc[0][1], 0, 0, 0);
        acc[1][0] = __builtin_amdgcn_mfma_f32_16x16x32_bf16(a1, b0, acc[1][0], 0, 0, 0);
        acc[1][1] = __builtin_amdgcn_mfma_f32_16x16x32_bf16(a1, b1, acc[1][1], 0, 0, 0);
    }
    __syncthreads();                           // norms visible

    // precompute the sqrt part into registers BEFORE waiting (post-barrier tail = sub+store)
    float sv[2][2][4];
    #pragma unroll
    for (int ci = 0; ci < 2; ++ci) {
        int lcb = wc + ci * 16 + q * 4;
        float nw0 = nB[lcb], nw1 = nB[lcb + 1], nw2 = nB[lcb + 2], nw3 = nB[lcb + 3];
        #pragma unroll
        for (int bj = 0; bj < 2; ++bj) {
            int lb = wb + bj * 16 + lm;
            float nb_ = nA[lb];
            floatx4 d = acc[ci][bj];
            sv[ci][bj][0] = sqrtf(fmaxf(nw0 + nb_ - 2.0f * d[0], 0.0f));
            sv[ci][bj][1] = sqrtf(fmaxf(nw1 + nb_ - 2.0f * d[1], 0.0f));
            sv[ci][bj][2] = sqrtf(fmaxf(nw2 + nb_ - 2.0f * d[2], 0.0f));
            sv[ci][bj][3] = sqrtf(fmaxf(nw3 + nb_ - 2.0f * d[3], 0.0f));
        }
    }

    // spin: RELAXED polls (no per-iteration cache invalidate); one acquire at the end
    if (t == 0) {
        while (__hip_atomic_load((int*)(ws + CNT_IDX), __ATOMIC_RELAXED,
                                 __HIP_MEMORY_SCOPE_AGENT) < NPROTO)
            __builtin_amdgcn_s_sleep(8);
        (void)__hip_atomic_load((int*)(ws + CNT_IDX), __ATOMIC_ACQUIRE,
                                __HIP_MEMORY_SCOPE_AGENT);
        __builtin_amdgcn_fence(__ATOMIC_ACQUIRE, "agent");
    }
    __syncthreads();
    float pv = (t < NPROTO)
        ? __hip_atomic_load(&ws[t], __ATOMIC_RELAXED, __HIP_MEMORY_SCOPE_AGENT)
        : 0.0f;
    #pragma unroll
    for (int off = 32; off > 0; off >>= 1) pv += __shfl_down(pv, off);
    if (lane == 0) red2[w] = pv;
    __syncthreads();
    float proto = red2[0] + red2[1] + red2[2] + red2[3];

    #pragma unroll
    for (int ci = 0; ci < 2; ++ci) {
        int lcb = wc + ci * 16 + q * 4;        // c_local base for this lane
        int cb  = col0 + lcb;                  // global c base (quad-aligned)
        if (cb < NC) {                         // NC%4==0: quad all-or-nothing
            #pragma unroll
            for (int bj = 0; bj < 2; ++bj) {
                int lb = wb + bj * 16 + lm;
                int bg = row0 + lb;            // global F row
                float4 o;
                o.x = proto - sv[ci][bj][0];
                o.y = proto - sv[ci][bj][1];
                o.z = proto - sv[ci][bj][2];
                o.w = proto - sv[ci][bj][3];
                *(float4*)(out + bg * NC + cb) = o;
            }
        }
    }
}

extern "C" void kernel_launch(void* const* d_in, const int* in_sizes, int n_in,
                              void* d_out, int out_size, void* d_ws, size_t ws_size,
                              hipStream_t stream) {
    const float* F  = (const float*)d_in[0];   // (2048,128)
    const float* Wm = (const float*)d_in[1];   // (1000,128)
    float* out = (float*)d_out;                // (2048,1000)
    float* ws  = (float*)d_ws;

    hipMemsetAsync((void*)(ws + CNT_IDX), 0, sizeof(int), stream);  // zero proto counter
    fused_kernel<<<NBLK, 256, 0, stream>>>(F, Wm, ws, out);
}

// Round 5
// 68.830 us; speedup vs baseline: 1.2304x; 1.1982x over previous
//
#include <hip/hip_runtime.h>
#include <hip/hip_bf16.h>
#include <math.h>

#define NB   2048
#define NC   1000
#define DDIM 128
#define LDT  136      // LDS row stride in bf16 (+8 pad; 272 B rows keep 16B align)
#define NPROTO 136    // compact triangular proto blocks (by<=bx<16), bid 0..135
#define NDIST  512    // dist tiles: 32 row-tiles x 16 col-tiles, bid 136..647
#define NBLK (NPROTO + NDIST)

typedef __attribute__((ext_vector_type(8))) short  short8;
typedef __attribute__((ext_vector_type(4))) float  floatx4;

__device__ __forceinline__ float bf2f(unsigned short b) {
    union { float f; unsigned int u; } v; v.u = ((unsigned int)b) << 16;
    return v.f;
}

// stage 64 rows x 128 k of fp32 -> bf16 LDS tile (RNE), coalesced float4 reads
__device__ __forceinline__ void stage_cvt(const float* __restrict__ src, int row0, int clampr,
                                          unsigned short* __restrict__ lds, int t) {
    #pragma unroll
    for (int i = 0; i < 8; ++i) {
        int c = (i * 256 + t) * 4;
        int r = c >> 7, k = c & 127;
        int gr = row0 + r; if (gr > clampr) gr = clampr;
        float4 v = *(const float4*)(src + gr * DDIM + k);
        union { __hip_bfloat162 h; unsigned int u; } p0, p1;
        p0.h = __float22bfloat162_rn(make_float2(v.x, v.y));
        p1.h = __float22bfloat162_rn(make_float2(v.z, v.w));
        uint2 st; st.x = p0.u; st.y = p1.u;
        *(uint2*)(lds + r * LDT + k) = st;
    }
}

// per-row squared norms of the ROUNDED bf16 values; 4 lanes per row
__device__ __forceinline__ void norm64(const unsigned short* __restrict__ tile,
                                       float* __restrict__ nrm, int t) {
    int r = t >> 2, seg = t & 3;
    const unsigned short* p = tile + r * LDT + seg * 32;
    float q = 0.0f;
    #pragma unroll
    for (int j = 0; j < 4; ++j) {
        short8 v = *(const short8*)(p + j * 8);
        #pragma unroll
        for (int e = 0; e < 8; ++e) { float f = bf2f((unsigned short)v[e]); q = fmaf(f, f, q); }
    }
    q += __shfl_xor(q, 1);
    q += __shfl_xor(q, 2);
    if (seg == 0) nrm[r] = q;
}

// ---- kernel 1: proto blocks (bid<136) and dist blocks (bid>=136), fully independent ----
// No atomics, no spinning: proto writes ws[bid]; dist writes s = sqrt(d2) to out.
__global__ __launch_bounds__(256) void main_kernel(const float* __restrict__ F,
                                                   const float* __restrict__ W,
                                                   float* __restrict__ ws,
                                                   float* __restrict__ out) {
    __shared__ __align__(16) unsigned short As[64 * LDT];
    __shared__ __align__(16) unsigned short Bs[64 * LDT];
    __shared__ float nA[64], nB[64], red[4];
    const int bid = blockIdx.x;
    const int t = threadIdx.x;
    const int lane = t & 63, w = t >> 6;
    const int lm = lane & 15, q = lane >> 4;

    if (bid < NPROTO) {
        // ---------- proto tile: compact upper triangle, bit-identical math ----------
        int by = 0, base = 0;                  // map bid -> (by<=bx<16)
        while (base + (16 - by) <= bid) { base += 16 - by; ++by; }
        int bx = by + (bid - base);
        int prow0 = by * 64, pcol0 = bx * 64;
        stage_cvt(W, prow0, NC - 1, As, t);
        stage_cvt(W, pcol0, NC - 1, Bs, t);
        __syncthreads();
        norm64(As, nA, t);
        norm64(Bs, nB, t);
        int wm = (w >> 1) * 32, wn = (w & 1) * 32;
        floatx4 acc[2][2] = {{{0,0,0,0},{0,0,0,0}},{{0,0,0,0},{0,0,0,0}}};
        #pragma unroll
        for (int ks = 0; ks < 4; ++ks) {
            int ko = ks * 32 + q * 8;
            short8 a0 = *(const short8*)(As + (wm + lm) * LDT + ko);
            short8 a1 = *(const short8*)(As + (wm + 16 + lm) * LDT + ko);
            short8 b0 = *(const short8*)(Bs + (wn + lm) * LDT + ko);
            short8 b1 = *(const short8*)(Bs + (wn + 16 + lm) * LDT + ko);
            acc[0][0] = __builtin_amdgcn_mfma_f32_16x16x32_bf16(a0, b0, acc[0][0], 0, 0, 0);
            acc[0][1] = __builtin_amdgcn_mfma_f32_16x16x32_bf16(a0, b1, acc[0][1], 0, 0, 0);
            acc[1][0] = __builtin_amdgcn_mfma_f32_16x16x32_bf16(a1, b0, acc[1][0], 0, 0, 0);
            acc[1][1] = __builtin_amdgcn_mfma_f32_16x16x32_bf16(a1, b1, acc[1][1], 0, 0, 0);
        }
        __syncthreads();                       // norms visible
        float local = 0.0f;
        #pragma unroll
        for (int ti = 0; ti < 2; ++ti)
            #pragma unroll
            for (int tj = 0; tj < 2; ++tj) {
                int lc2 = wn + tj * 16 + lm;
                if (pcol0 + lc2 < NC) {
                    float n2 = nB[lc2];
                    #pragma unroll
                    for (int r = 0; r < 4; ++r) {
                        int lc1 = wm + ti * 16 + q * 4 + r;
                        if (prow0 + lc1 < NC) {
                            float d2 = nA[lc1] + n2 - 2.0f * acc[ti][tj][r];
                            local += sqrtf(fmaxf(d2, 0.0f));
                        }
                    }
                }
            }
        if (by != bx) local *= 2.0f;           // symmetric double-count
        #pragma unroll
        for (int off = 32; off > 0; off >>= 1) local += __shfl_down(local, off);
        if (lane == 0) red[w] = local;
        __syncthreads();
        if (t == 0) ws[bid] = red[0] + red[1] + red[2] + red[3];   // plain store
        return;                                // proto blocks done
    }

    // ---------- dist tile: swapped operands (m=c, n=b); stores s = sqrt(d2) ----------
    const int did  = bid - NPROTO;             // 0..511
    const int row0 = (did >> 4) * 64;          // F rows
    const int col0 = (did & 15) * 64;          // W rows
    stage_cvt(F, row0, NB - 1, As, t);         // As = F tile
    stage_cvt(W, col0, NC - 1, Bs, t);         // Bs = W tile
    __syncthreads();                           // staging visible
    norm64(As, nA, t);                         // nA = F norms
    norm64(Bs, nB, t);                         // nB = W norms
    int wc = (w >> 1) * 32, wb = (w & 1) * 32; // wave offsets: c (m-dim), b (n-dim)
    floatx4 acc[2][2] = {{{0,0,0,0},{0,0,0,0}},{{0,0,0,0},{0,0,0,0}}};
    #pragma unroll
    for (int ks = 0; ks < 4; ++ks) {
        int ko = ks * 32 + q * 8;
        short8 a0 = *(const short8*)(Bs + (wc + lm) * LDT + ko);       // A-frag = W
        short8 a1 = *(const short8*)(Bs + (wc + 16 + lm) * LDT + ko);
        short8 b0 = *(const short8*)(As + (wb + lm) * LDT + ko);       // B-frag = F
        short8 b1 = *(const short8*)(As + (wb + 16 + lm) * LDT + ko);
        acc[0][0] = __builtin_amdgcn_mfma_f32_16x16x32_bf16(a0, b0, acc[0][0], 0, 0, 0);
        acc[0][1] = __builtin_amdgcn_mfma_f32_16x16x32_bf16(a0, b1, acc[0][1], 0, 0, 0);
        acc[1][0] = __builtin_amdgcn_mfma_f32_16x16x32_bf16(a1, b0, acc[1][0], 0, 0, 0);
        acc[1][1] = __builtin_amdgcn_mfma_f32_16x16x32_bf16(a1, b1, acc[1][1], 0, 0, 0);
    }
    __syncthreads();                           // norms visible

    #pragma unroll
    for (int ci = 0; ci < 2; ++ci) {
        int lcb = wc + ci * 16 + q * 4;        // c_local base for this lane
        int cb  = col0 + lcb;                  // global c base (quad-aligned)
        if (cb < NC) {                         // NC%4==0: quad all-or-nothing
            float nw0 = nB[lcb], nw1 = nB[lcb + 1], nw2 = nB[lcb + 2], nw3 = nB[lcb + 3];
            #pragma unroll
            for (int bj = 0; bj < 2; ++bj) {
                int lb = wb + bj * 16 + lm;
                int bg = row0 + lb;            // global F row
                float nb_ = nA[lb];
                floatx4 d = acc[ci][bj];
                float4 o;                      // store s; epilogue does proto - s
                o.x = sqrtf(fmaxf(nw0 + nb_ - 2.0f * d[0], 0.0f));
                o.y = sqrtf(fmaxf(nw1 + nb_ - 2.0f * d[1], 0.0f));
                o.z = sqrtf(fmaxf(nw2 + nb_ - 2.0f * d[2], 0.0f));
                o.w = sqrtf(fmaxf(nw3 + nb_ - 2.0f * d[3], 0.0f));
                *(float4*)(out + bg * NC + cb) = o;
            }
        }
    }
}

// ---- kernel 2: reduce 136 partials (bit-identical order) and apply proto - s ----
__global__ __launch_bounds__(256) void add_kernel(const float* __restrict__ ws,
                                                  float* __restrict__ out) {
    __shared__ float red2[4];
    const int t = threadIdx.x;
    const int lane = t & 63, w = t >> 6;
    float pv = (t < NPROTO) ? ws[t] : 0.0f;
    #pragma unroll
    for (int off = 32; off > 0; off >>= 1) pv += __shfl_down(pv, off);
    if (lane == 0) red2[w] = pv;
    __syncthreads();
    float proto = red2[0] + red2[1] + red2[2] + red2[3];

    int i = blockIdx.x * 256 + t;              // grid 2000x256 = exactly NB*NC/4 float4
    float4 v = ((const float4*)out)[i];
    v.x = proto - v.x;
    v.y = proto - v.y;
    v.z = proto - v.z;
    v.w = proto - v.w;
    ((float4*)out)[i] = v;
}

extern "C" void kernel_launch(void* const* d_in, const int* in_sizes, int n_in,
                              void* d_out, int out_size, void* d_ws, size_t ws_size,
                              hipStream_t stream) {
    const float* F  = (const float*)d_in[0];   // (2048,128)
    const float* Wm = (const float*)d_in[1];   // (1000,128)
    float* out = (float*)d_out;                // (2048,1000)
    float* ws  = (float*)d_ws;

    main_kernel<<<NBLK, 256, 0, stream>>>(F, Wm, ws, out);
    add_kernel<<<NB * NC / 4 / 256, 256, 0, stream>>>(ws, out);   // 2000 blocks
}

// Round 6
// 67.564 us; speedup vs baseline: 1.2535x; 1.0187x over previous
//
#include <hip/hip_runtime.h>
#include <hip/hip_bf16.h>
#include <math.h>

#define NB   2048
#define NC   1000
#define DDIM 128
#define LDT  136      // LDS row stride in bf16 (+8 pad; 272 B rows keep 16B align)
#define NPB  136      // compact triangular proto blocks (by<=bx<16)

typedef __attribute__((ext_vector_type(8))) short  short8;
typedef __attribute__((ext_vector_type(4))) float  floatx4;

__device__ __forceinline__ float bf2f(unsigned short b) {
    union { float f; unsigned int u; } v; v.u = ((unsigned int)b) << 16;
    return v.f;
}

// stage 64 rows x 128 k of fp32 -> bf16 LDS tile (RNE), coalesced float4 reads
__device__ __forceinline__ void stage_cvt(const float* __restrict__ src, int row0, int clampr,
                                          unsigned short* __restrict__ lds, int t) {
    #pragma unroll
    for (int i = 0; i < 8; ++i) {
        int c = (i * 256 + t) * 4;
        int r = c >> 7, k = c & 127;
        int gr = row0 + r; if (gr > clampr) gr = clampr;
        float4 v = *(const float4*)(src + gr * DDIM + k);
        union { __hip_bfloat162 h; unsigned int u; } p0, p1;
        p0.h = __float22bfloat162_rn(make_float2(v.x, v.y));
        p1.h = __float22bfloat162_rn(make_float2(v.z, v.w));
        uint2 st; st.x = p0.u; st.y = p1.u;
        *(uint2*)(lds + r * LDT + k) = st;
    }
}

// stage 32 rows x 128 k (same value-path as stage_cvt, 4 iters)
__device__ __forceinline__ void stage_cvt32(const float* __restrict__ src, int row0, int clampr,
                                            unsigned short* __restrict__ lds, int t) {
    #pragma unroll
    for (int i = 0; i < 4; ++i) {
        int c = (i * 256 + t) * 4;
        int r = c >> 7, k = c & 127;
        int gr = row0 + r; if (gr > clampr) gr = clampr;
        float4 v = *(const float4*)(src + gr * DDIM + k);
        union { __hip_bfloat162 h; unsigned int u; } p0, p1;
        p0.h = __float22bfloat162_rn(make_float2(v.x, v.y));
        p1.h = __float22bfloat162_rn(make_float2(v.z, v.w));
        uint2 st; st.x = p0.u; st.y = p1.u;
        *(uint2*)(lds + r * LDT + k) = st;
    }
}

// per-row squared norms of the ROUNDED bf16 values; 4 lanes per row (64 rows)
__device__ __forceinline__ void norm64(const unsigned short* __restrict__ tile,
                                       float* __restrict__ nrm, int t) {
    int r = t >> 2, seg = t & 3;
    const unsigned short* p = tile + r * LDT + seg * 32;
    float q = 0.0f;
    #pragma unroll
    for (int j = 0; j < 4; ++j) {
        short8 v = *(const short8*)(p + j * 8);
        #pragma unroll
        for (int e = 0; e < 8; ++e) { float f = bf2f((unsigned short)v[e]); q = fmaf(f, f, q); }
    }
    q += __shfl_xor(q, 1);
    q += __shfl_xor(q, 2);
    if (seg == 0) nrm[r] = q;
}

// ---- proto: compact upper-triangle 64x64 tiles, partial -> ws[bid] (unchanged) ----
__global__ __launch_bounds__(256) void proto_kernel(const float* __restrict__ W,
                                                    float* __restrict__ ws) {
    __shared__ __align__(16) unsigned short As[64 * LDT];
    __shared__ __align__(16) unsigned short Bs[64 * LDT];
    __shared__ float nA[64], nB[64], red[4];
    int bid = blockIdx.x;
    int by = 0, base = 0;                      // map bid -> (by<=bx<16)
    while (base + (16 - by) <= bid) { base += 16 - by; ++by; }
    int bx = by + (bid - base);
    int t = threadIdx.x;
    int row0 = by * 64, col0 = bx * 64;
    stage_cvt(W, row0, NC - 1, As, t);
    stage_cvt(W, col0, NC - 1, Bs, t);
    __syncthreads();
    norm64(As, nA, t);
    norm64(Bs, nB, t);
    int lane = t & 63, w = t >> 6;
    int wm = (w >> 1) * 32, wn = (w & 1) * 32;
    int lm = lane & 15, q = lane >> 4;
    floatx4 acc[2][2] = {{{0,0,0,0},{0,0,0,0}},{{0,0,0,0},{0,0,0,0}}};
    #pragma unroll
    for (int ks = 0; ks < 4; ++ks) {
        int ko = ks * 32 + q * 8;
        short8 a0 = *(const short8*)(As + (wm + lm) * LDT + ko);
        short8 a1 = *(const short8*)(As + (wm + 16 + lm) * LDT + ko);
        short8 b0 = *(const short8*)(Bs + (wn + lm) * LDT + ko);
        short8 b1 = *(const short8*)(Bs + (wn + 16 + lm) * LDT + ko);
        acc[0][0] = __builtin_amdgcn_mfma_f32_16x16x32_bf16(a0, b0, acc[0][0], 0, 0, 0);
        acc[0][1] = __builtin_amdgcn_mfma_f32_16x16x32_bf16(a0, b1, acc[0][1], 0, 0, 0);
        acc[1][0] = __builtin_amdgcn_mfma_f32_16x16x32_bf16(a1, b0, acc[1][0], 0, 0, 0);
        acc[1][1] = __builtin_amdgcn_mfma_f32_16x16x32_bf16(a1, b1, acc[1][1], 0, 0, 0);
    }
    __syncthreads();                           // norms visible
    float local = 0.0f;
    #pragma unroll
    for (int ti = 0; ti < 2; ++ti)
        #pragma unroll
        for (int tj = 0; tj < 2; ++tj) {
            int lc2 = wn + tj * 16 + lm;
            if (col0 + lc2 < NC) {
                float n2 = nB[lc2];
                #pragma unroll
                for (int r = 0; r < 4; ++r) {
                    int lc1 = wm + ti * 16 + q * 4 + r;
                    if (row0 + lc1 < NC) {
                        float d2 = nA[lc1] + n2 - 2.0f * acc[ti][tj][r];
                        local += sqrtf(fmaxf(d2, 0.0f));
                    }
                }
            }
        }
    if (by != bx) local *= 2.0f;               // symmetric double-count
    #pragma unroll
    for (int off = 32; off > 0; off >>= 1) local += __shfl_down(local, off);
    if (lane == 0) red[w] = local;
    __syncthreads();
    if (t == 0) ws[bid] = red[0] + red[1] + red[2] + red[3];
}

// ---- dist: 32x32 tiles, 2048 blocks (8 blocks/CU -> full occupancy) -------------
// same per-element math as before: m=c (A=W), n=b (B=F), float4 stores over c
__global__ __launch_bounds__(256) void dist_kernel(const float* __restrict__ F,
                                                   const float* __restrict__ W,
                                                   const float* __restrict__ ws,
                                                   float* __restrict__ out) {
    __shared__ __align__(16) unsigned short Fs[32 * LDT];
    __shared__ __align__(16) unsigned short Ws[32 * LDT];
    __shared__ float nF[32], nW[32], red2[4];
    int t = threadIdx.x;
    int row0 = blockIdx.y * 32;                // F rows (b), 64 tiles
    int col0 = blockIdx.x * 32;                // W rows (c), 32 tiles (992+32 > 1000, checked)

    float pv = (t < NPB) ? ws[t] : 0.0f;       // proto partials (coalesced 544 B)
    stage_cvt32(F, row0, NB - 1, Fs, t);
    stage_cvt32(W, col0, NC - 1, Ws, t);
    #pragma unroll
    for (int off = 32; off > 0; off >>= 1) pv += __shfl_down(pv, off);
    if ((t & 63) == 0) red2[t >> 6] = pv;
    __syncthreads();                           // staging + red2 visible
    float proto = red2[0] + red2[1] + red2[2] + red2[3];

    // norms: threads 0..127 -> F rows, 128..255 -> W rows; identical 4-lane/row math
    {
        int rr = t >> 2, seg = t & 3;
        const unsigned short* p = (t < 128) ? (Fs + rr * LDT + seg * 32)
                                            : (Ws + (rr - 32) * LDT + seg * 32);
        float q2 = 0.0f;
        #pragma unroll
        for (int j = 0; j < 4; ++j) {
            short8 v = *(const short8*)(p + j * 8);
            #pragma unroll
            for (int e = 0; e < 8; ++e) { float f = bf2f((unsigned short)v[e]); q2 = fmaf(f, f, q2); }
        }
        q2 += __shfl_xor(q2, 1);
        q2 += __shfl_xor(q2, 2);
        if (seg == 0) { if (t < 128) nF[rr] = q2; else nW[rr - 32] = q2; }
    }

    int lane = t & 63, w = t >> 6;
    int lm = lane & 15, q = lane >> 4;
    int wc = (w & 1) * 16;                     // this wave's c sub-tile (m-dim)
    int wb = (w >> 1) * 16;                    // this wave's b sub-tile (n-dim)
    floatx4 acc = {0, 0, 0, 0};
    #pragma unroll
    for (int ks = 0; ks < 4; ++ks) {
        int ko = ks * 32 + q * 8;
        short8 a = *(const short8*)(Ws + (wc + lm) * LDT + ko);   // A-frag = W
        short8 b = *(const short8*)(Fs + (wb + lm) * LDT + ko);   // B-frag = F
        acc = __builtin_amdgcn_mfma_f32_16x16x32_bf16(a, b, acc, 0, 0, 0);
    }
    __syncthreads();                           // norms visible

    int lcb = wc + q * 4;                      // c_local base for this lane
    int cb  = col0 + lcb;                      // global c base (quad-aligned)
    if (cb < NC) {                             // NC%4==0: quad all-or-nothing
        float nw0 = nW[lcb], nw1 = nW[lcb + 1], nw2 = nW[lcb + 2], nw3 = nW[lcb + 3];
        int lb = wb + lm;
        int bg = row0 + lb;                    // global F row
        float nb_ = nF[lb];
        float4 o;
        o.x = proto - sqrtf(fmaxf(nw0 + nb_ - 2.0f * acc[0], 0.0f));
        o.y = proto - sqrtf(fmaxf(nw1 + nb_ - 2.0f * acc[1], 0.0f));
        o.z = proto - sqrtf(fmaxf(nw2 + nb_ - 2.0f * acc[2], 0.0f));
        o.w = proto - sqrtf(fmaxf(nw3 + nb_ - 2.0f * acc[3], 0.0f));
        *(float4*)(out + bg * NC + cb) = o;
    }
}

extern "C" void kernel_launch(void* const* d_in, const int* in_sizes, int n_in,
                              void* d_out, int out_size, void* d_ws, size_t ws_size,
                              hipStream_t stream) {
    const float* F  = (const float*)d_in[0];   // (2048,128)
    const float* Wm = (const float*)d_in[1];   // (1000,128)
    float* out = (float*)d_out;                // (2048,1000)
    float* ws  = (float*)d_ws;

    proto_kernel<<<NPB, 256, 0, stream>>>(Wm, ws);                      // 136 partials
    dist_kernel <<<dim3(32, 64), 256, 0, stream>>>(F, Wm, ws, out);     // 2048 tiles
}